// Round 12
// baseline (129.774 us; speedup 1.0000x reference)
//
#include <hip/hip_runtime.h>
#include <hip/hip_bf16.h>

// Problem constants: B=4, T=4096, C=1024, H=16, D=64
#define BB 4
#define TT 4096
#define CC 1024
#define HH 16
#define DD 64

typedef __attribute__((ext_vector_type(8))) short short8;
typedef __attribute__((ext_vector_type(8))) __bf16 bf16x8;
typedef __attribute__((ext_vector_type(4))) float f32x4;

static __device__ __forceinline__ unsigned short f2bf(float f) {
    unsigned int u = __builtin_bit_cast(unsigned int, f);
    unsigned int r = (u + 0x7FFFu + ((u >> 16) & 1u)) >> 16;
    return (unsigned short)r;
}
static __device__ __forceinline__ float bf2f(unsigned short h) {
    return __builtin_bit_cast(float, ((unsigned int)h) << 16);
}

// ---------------- fp32 -> bf16 conversion ----------------
__global__ void k_f32_to_bf16(const float* __restrict__ src,
                              unsigned short* __restrict__ dst, int n4) {
    int i = blockIdx.x * 256 + threadIdx.x;
    if (i >= n4) return;
    float4 v = ((const float4*)src)[i];
    ushort4 o;
    o.x = f2bf(v.x); o.y = f2bf(v.y); o.z = f2bf(v.z); o.w = f2bf(v.w);
    ((ushort4*)dst)[i] = o;
}

// ================= 256x256 single-phase-per-K-tile bf16 GEMM =================
// C[m,n] = sum_k A[m,k]*B[n,k] + bias[n];  A: MxK, B: NxK row-major bf16.
// 8 waves (2M x 4N), per-wave output 128x64. BK=32.
// 4-slab LDS rotation (4 x 32KB). Per K-tile (ONE barrier, ONE counted vmcnt):
//   vmcnt(8)   -> drains S(kt-3): slab kt&3 fully landed (4 gloads/tile FIFO)
//   s_barrier  -> all waves agree slab kt&3 is ready
//   12 ds_read_b128 (af[8], bf[4])          | compiler emits per-dep lgkmcnt
//   stage slab (kt+3)&3 (4 global_load_lds) | overlaps with MFMA below
//   setprio(1); 32 MFMA; setprio(0)
// Race-freedom: S(kt) writes slab (kt+3)&3; its last readers (tile kt-1)
// consumed their ds_reads in MFMA(kt-1) BEFORE this tile's barrier.
// MODE 0: C written bf16 + fused column sum-of-squares S (B shared).
// MODE 1: C fp32, B is PER-BATCH (Wp' holds attnScale fold): Bbase += b*N*K.
#define GBM 256
#define GBN 256
#define GBK 32

static __device__ __forceinline__ void stage_tile32(
    const unsigned short* __restrict__ Gbase, unsigned short* lbase,
    int k0, int K, int wave, int lane)
{
    #pragma unroll
    for (int q = 0; q < 2; ++q) {
        int c = (wave * 2 + q) * 64 + lane;
        int r = c >> 2;
        int j = c & 3;
        int srcj = (j - (r >> 1)) & 3;
        const unsigned short* g = Gbase + (size_t)r * K + k0 + srcj * 8;
        __builtin_amdgcn_global_load_lds(
            (const __attribute__((address_space(1))) void*)g,
            (__attribute__((address_space(3))) void*)(lbase + (wave * 2 + q) * 512),
            16, 0, 0);
    }
}

template<int MODE>
__global__ __launch_bounds__(512, 2)
void k_gemm256(const unsigned short* __restrict__ A,
               const unsigned short* __restrict__ B,
               const float* __restrict__ bias,
               void* __restrict__ Cout,
               float* __restrict__ S,
               int M, int N, int K)
{
    // per slab: A tile [256][32] = 8192 ushorts, then B tile 8192 ushorts
    __shared__ unsigned short lds[4][16384];   // 128 KB
    const int tid  = threadIdx.x;
    const int wave = tid >> 6;
    const int lane = tid & 63;
    const int wr = wave >> 2;   // 0..1
    const int wc = wave & 3;    // 0..3
    const int fr = lane & 15;
    const int hi = lane >> 4;   // 0..3

    // XCD-aware bijective swizzle (256 blocks, 8 XCDs, chunk=32, bn fastest)
    const int wg  = blockIdx.x;
    const int swz = (wg & 7) * 32 + (wg >> 3);
    const int bn  = swz & 3;
    const int bm  = swz >> 2;
    const int b   = bm >> 4;    // batch (16 bm-tiles per batch)

    const unsigned short* Abase = A + (size_t)(bm * GBM) * K;
    const unsigned short* Bbase = B +
        ((size_t)((MODE == 1 ? b * N : 0) + bn * GBN)) * K;

    const int nt = K / GBK;   // 32

    // per-lane constant read offsets (ushort idx):
    const int sl   = (hi + (fr >> 1)) & 3;
    const int aoff = (wr * 128 + fr) * 32 + sl * 8;          // + mi*512
    const int boff = 8192 + (wc * 64 + fr) * 32 + sl * 8;    // + ni*512

    f32x4 acc[8][4] = {};

    // ---- prologue: stage slabs 0,1,2 (12 gloads in flight) ----
    stage_tile32(Abase, lds[0],        0,       K, wave, lane);
    stage_tile32(Bbase, lds[0] + 8192, 0,       K, wave, lane);
    stage_tile32(Abase, lds[1],        GBK,     K, wave, lane);
    stage_tile32(Bbase, lds[1] + 8192, GBK,     K, wave, lane);
    stage_tile32(Abase, lds[2],        2 * GBK, K, wave, lane);
    stage_tile32(Bbase, lds[2] + 8192, 2 * GBK, K, wave, lane);

    for (int kt = 0; kt < nt; ++kt) {
        const unsigned short* buf = lds[kt & 3];
        unsigned short* sbuf = lds[(kt + 3) & 3];
        int k3 = kt + 3; if (k3 >= nt) k3 = nt - 1;

        // counted wait: keeps newest 8 VMEM ops (slabs kt+1, kt+2) in flight,
        // drains S(kt-3) -> slab kt&3 landed. Then all waves agree.
        asm volatile("s_waitcnt vmcnt(8)" ::: "memory");
        __builtin_amdgcn_s_barrier();

        short8 af[8], bfr[4];
        #pragma unroll
        for (int i = 0; i < 4; ++i) bfr[i] = *(const short8*)&buf[boff + i * 512];
        #pragma unroll
        for (int i = 0; i < 8; ++i) af[i] = *(const short8*)&buf[aoff + i * 512];

        // stage slab (kt+3)&3: readers of that slab (tile kt-1) drained
        // their reads before this tile's barrier -> race-free.
        stage_tile32(Abase, sbuf, k3 * GBK, K, wave, lane);
        stage_tile32(Bbase, sbuf + 8192, k3 * GBK, K, wave, lane);

        __builtin_amdgcn_s_setprio(1);
        #pragma unroll
        for (int mi = 0; mi < 8; ++mi)
            #pragma unroll
            for (int ni = 0; ni < 4; ++ni)
                acc[mi][ni] = __builtin_amdgcn_mfma_f32_16x16x32_bf16(
                    __builtin_bit_cast(bf16x8, af[mi]),
                    __builtin_bit_cast(bf16x8, bfr[ni]),
                    acc[mi][ni], 0, 0, 0);
        __builtin_amdgcn_s_setprio(0);
    }

    __syncthreads();   // full drain (vmcnt+lgkmcnt) before LDS reuse

    // ---- epilogue: C/D layout col=lane&15, row=(lane>>4)*4+j ----
    const int cg = fr;
    const int rg = hi * 4;
    float* sblk = (float*)&lds[0][0];
    if (MODE == 0) {
        if (tid < GBN) sblk[tid] = 0.f;
        __syncthreads();
    }
    float csum[4] = {};
    #pragma unroll
    for (int mi = 0; mi < 8; ++mi) {
        #pragma unroll
        for (int ni = 0; ni < 4; ++ni) {
            int col = bn * GBN + wc * 64 + ni * 16 + cg;
            float bv = bias[col];
            #pragma unroll
            for (int j = 0; j < 4; ++j) {
                int row = bm * GBM + wr * 128 + mi * 16 + rg + j;
                float v = acc[mi][ni][j] + bv;
                if (MODE == 0) {
                    ((unsigned short*)Cout)[(size_t)row * N + col] = f2bf(v);
                    csum[ni] += v * v;
                } else {
                    ((float*)Cout)[(size_t)row * N + col] = v;
                }
            }
        }
    }
    if (MODE == 0) {
        #pragma unroll
        for (int ni = 0; ni < 4; ++ni)
            atomicAdd(&sblk[wc * 64 + ni * 16 + cg], csum[ni]);
        __syncthreads();
        if (tid < GBN) atomicAdd(&S[b * CC + bn * GBN + tid], sblk[tid]);
    }
}

// ------- per-row softmax over heads + IN-PLACE y = bf16(-(w*Pi)) -------
__global__ __launch_bounds__(256)
void k_row_softmax(unsigned short* __restrict__ w16, const float* __restrict__ S,
                   const float* __restrict__ temp,
                   float* __restrict__ dotsU, float* __restrict__ sumPi)
{
    __shared__ float dots_local[CC];
    __shared__ float sPi_local[HH];
    const int tid  = threadIdx.x;
    const int wave = tid >> 6;
    const int lane = tid & 63;
    const int bb   = blockIdx.x >> 7;
    const int tile = blockIdx.x & 127;

    for (int c = tid; c < CC; c += 256) dots_local[c] = 0.f;
    if (tid < HH) sPi_local[tid] = 0.f;
    __syncthreads();

    const int g3 = lane >> 3;
    const int li = lane & 7;

    float inv[2][8], tsc[2];
    #pragma unroll
    for (int q = 0; q < 2; ++q) {
        int c = q * 512 + lane * 8;
        const float4* sp = (const float4*)&S[bb * CC + c];
        float4 s0 = sp[0], s1 = sp[1];
        inv[q][0] = 1.f / fmaxf(s0.x, 1e-24f); inv[q][1] = 1.f / fmaxf(s0.y, 1e-24f);
        inv[q][2] = 1.f / fmaxf(s0.z, 1e-24f); inv[q][3] = 1.f / fmaxf(s0.w, 1e-24f);
        inv[q][4] = 1.f / fmaxf(s1.x, 1e-24f); inv[q][5] = 1.f / fmaxf(s1.y, 1e-24f);
        inv[q][6] = 1.f / fmaxf(s1.z, 1e-24f); inv[q][7] = 1.f / fmaxf(s1.w, 1e-24f);
        tsc[q] = temp[q * 8 + g3];
    }

    float dacc[2][8] = {};
    float sPiAcc[2] = {};

    for (int i = 0; i < 8; ++i) {
        int t = tile * 32 + wave * 8 + i;
        unsigned short* row = w16 + ((size_t)bb * TT + t) * CC;
        float wf[2][8];
        float pq[2];
        #pragma unroll
        for (int q = 0; q < 2; ++q) {
            short8 v = *(const short8*)&row[q * 512 + lane * 8];
            float s = 0.f;
            #pragma unroll
            for (int j = 0; j < 8; ++j) {
                wf[q][j] = bf2f((unsigned short)v[j]);
                s += wf[q][j] * wf[q][j] * inv[q][j];
            }
            pq[q] = s;
        }
        #pragma unroll
        for (int off = 1; off < 8; off <<= 1) {
            pq[0] += __shfl_xor(pq[0], off);
            pq[1] += __shfl_xor(pq[1], off);
        }
        pq[0] *= tsc[0]; pq[1] *= tsc[1];
        float mx = fmaxf(pq[0], pq[1]);
        mx = fmaxf(mx, __shfl_xor(mx, 8));
        mx = fmaxf(mx, __shfl_xor(mx, 16));
        mx = fmaxf(mx, __shfl_xor(mx, 32));
        float e0 = __expf(pq[0] - mx), e1 = __expf(pq[1] - mx);
        float ss = e0 + e1;
        ss += __shfl_xor(ss, 8);
        ss += __shfl_xor(ss, 16);
        ss += __shfl_xor(ss, 32);
        float rs = 1.f / ss;
        float piv[2] = { e0 * rs, e1 * rs };
        #pragma unroll
        for (int q = 0; q < 2; ++q) {
            short8 yo;
            #pragma unroll
            for (int j = 0; j < 8; ++j) {
                dacc[q][j] += piv[q] * wf[q][j] * wf[q][j];
                yo[j] = (short)f2bf(-wf[q][j] * piv[q]);
            }
            *(short8*)&row[q * 512 + lane * 8] = yo;   // in-place y = -(w*Pi)
            if (li == 0) sPiAcc[q] += piv[q];
        }
    }

    #pragma unroll
    for (int q = 0; q < 2; ++q) {
        int c = q * 512 + lane * 8;
        #pragma unroll
        for (int j = 0; j < 8; ++j)
            atomicAdd(&dots_local[c + j], dacc[q][j]);
        if (li == 0) atomicAdd(&sPi_local[q * 8 + g3], sPiAcc[q]);
    }
    __syncthreads();
    for (int c = tid; c < CC; c += 256) atomicAdd(&dotsU[bb * CC + c], dots_local[c]);
    if (tid < HH) atomicAdd(&sumPi[bb * HH + tid], sPi_local[tid]);
}

// -- Wp'[b,n,c] = bf16( Wp[n,c] * (+1/(1 + dotsU[b,c]/(sumPi[b,h]+1e-8))) ) --
// (sign: y already carries the minus)
__global__ void k_scale_wproj(const float* __restrict__ Wp,
                              const float* __restrict__ dotsU,
                              const float* __restrict__ sumPi,
                              unsigned short* __restrict__ out)
{
    int i = blockIdx.x * 256 + threadIdx.x;   // 1,048,576 groups of 4
    int bq  = i >> 18;                        // batch
    int rem = i & 262143;
    int n   = rem >> 8;
    int cg  = (rem & 255) * 4;
    float4 wv = *(const float4*)&Wp[n * CC + cg];
    float4 du = *(const float4*)&dotsU[bq * CC + cg];
    float sp = sumPi[bq * HH + (cg >> 6)] + 1e-8f;
    float a0 = 1.f / (1.f + du.x / sp);
    float a1 = 1.f / (1.f + du.y / sp);
    float a2 = 1.f / (1.f + du.z / sp);
    float a3 = 1.f / (1.f + du.w / sp);
    ushort4 o;
    o.x = f2bf(wv.x * a0); o.y = f2bf(wv.y * a1);
    o.z = f2bf(wv.z * a2); o.w = f2bf(wv.w * a3);
    *(ushort4*)&out[((size_t)bq * CC + n) * CC + cg] = o;
}

// ---------------- launch ----------------
extern "C" void kernel_launch(void* const* d_in, const int* in_sizes, int n_in,
                              void* d_out, int out_size, void* d_ws, size_t ws_size,
                              hipStream_t stream) {
    const float* x      = (const float*)d_in[0];
    const float* W_attn = (const float*)d_in[1];
    const float* b_attn = (const float*)d_in[2];
    const float* W_proj = (const float*)d_in[3];
    const float* b_proj = (const float*)d_in[4];
    const float* temp   = (const float*)d_in[5];

    // xb (x as bf16, 32MB) lives in the FIRST HALF of d_out: fully dead before
    // GEMM2 overwrites d_out with the fp32 result.
    unsigned short* xb = (unsigned short*)d_out;

    char* ws = (char*)d_ws;
    unsigned short* w16   = (unsigned short*)(ws);             // 33554432 B (w, then y in-place)
    unsigned short* Wa16  = (unsigned short*)(ws + 33554432);  // 2097152 B
    unsigned short* Wp16b = (unsigned short*)(ws + 35651584);  // 8388608 B (per-batch Wp')
    float* S     = (float*)(ws + 44040192);  // 16384 B
    float* dotsU = (float*)(ws + 44056576);  // 16384 B
    float* sumPi = (float*)(ws + 44072960);  // 256 B

    // conversions
    k_f32_to_bf16<<<dim3(16384), dim3(256), 0, stream>>>(x, xb, 4194304);
    k_f32_to_bf16<<<dim3(1024), dim3(256), 0, stream>>>(W_attn, Wa16, 262144);

    // zero accumulators (S, dotsU, sumPi contiguous)
    hipMemsetAsync(S, 0, 16384 + 16384 + 256, stream);

    // GEMM1: w16 = bf16(xb @ Wa^T + b_attn); fused S[b,c] = sum_t w^2
    k_gemm256<0><<<dim3(256), dim3(512), 0, stream>>>(
        xb, Wa16, b_attn, w16, S, BB * TT, CC, CC);

    // head-softmax per token; in-place w16 <- bf16(-(w*Pi)); dotsU, sumPi
    k_row_softmax<<<dim3(512), dim3(256), 0, stream>>>(w16, S, temp, dotsU, sumPi);

    // per-batch projection weights with attn fold: Wp'[b] = attn ⊙ Wp
    k_scale_wproj<<<dim3(4096), dim3(256), 0, stream>>>(W_proj, dotsU, sumPi, Wp16b);

    // GEMM2: out = y @ Wp'[b]^T + b_proj (fp32, overwrites xb region of d_out)
    k_gemm256<1><<<dim3(256), dim3(512), 0, stream>>>(
        w16, Wp16b, b_proj, d_out, nullptr, BB * TT, CC, CC);
}